// Round 2
// baseline (2130.368 us; speedup 1.0000x reference)
//
#include <hip/hip_runtime.h>

// Causal GQA attention prefill, fp32 in/out, fp32 accumulate.
// S=2048, H=32, KVH=8 (rep=4), D=128, scale=1/sqrt(128).
// Round 2: same flash structure as round 1, ported to fp32 I/O.
//   (Round 1 NaN diagnosed as dtype mismatch: inputs are float32 per the
//    reference setup_inputs, not bf16 — bf16 decode of fp32 bits => NaN.)
//   block = 256 threads = 4 waves; wave w owns query row blockIdx.x*4 + w.
//   All 4 rows share one head -> one KV head -> shared K/V LDS tiles (64 keys).

#define SEQ   2048
#define NH    32
#define NKVH  8
#define HD    128
#define TS    64            // key tile
#define KROWF 132           // float row stride (128 + 4 -> 16B-aligned pad)
#define SCALE 0.08838834764831845f

__global__ __launch_bounds__(256)
void attn_fwd(const float* __restrict__ q,
              const float* __restrict__ k,
              const float* __restrict__ v,
              float* __restrict__ out)
{
    __shared__ float ks[TS * KROWF];
    __shared__ float vs[TS * KROWF];
    __shared__ float qs[4 * HD];
    __shared__ float ps[4 * TS];

    const int t    = threadIdx.x;
    const int w    = t >> 6;        // wave 0..3
    const int lane = t & 63;
    const int h    = blockIdx.y;
    const int kvh  = h >> 2;        // rep = 4 (repeat_interleave)
    const int q0   = blockIdx.x * 4;
    const int qrow = q0 + w;

    // Stage this wave's q row into LDS (float2 per lane, coalesced).
    {
        const float2 qu =
            *(const float2*)(q + ((size_t)qrow * NH + h) * HD + 2 * lane);
        qs[w * HD + 2 * lane]     = qu.x;
        qs[w * HD + 2 * lane + 1] = qu.y;
    }

    float m_run = -1e30f, l_run = 0.f, acc0 = 0.f, acc1 = 0.f;
    const int ntiles = q0 / TS + 1;   // uniform across the block (4 | 64)

    for (int it = 0; it < ntiles; ++it) {
        const int j0 = it * TS;
        __syncthreads();   // previous tile's PV reads done before overwrite

        // Stage K/V tile: 64 keys x 128 d, float4 per thread x8 per matrix.
        {
            const int jj = t >> 5;           // 0..7
            const int dd = (t & 31) * 4;     // 0..124
            #pragma unroll
            for (int r = 0; r < 8; ++r) {
                const int j = r * 8 + jj;
                const size_t g = ((size_t)(j0 + j) * NKVH + kvh) * HD + dd;
                *(float4*)&ks[j * KROWF + dd] = *(const float4*)(k + g);
                *(float4*)&vs[j * KROWF + dd] = *(const float4*)(v + g);
            }
        }
        __syncthreads();

        // ---- scores: lane = key j0+lane, dot over D=128 ----
        float s = 0.f;
        const float* kr = &ks[lane * KROWF];
        const float* qr = &qs[w * HD];
        #pragma unroll
        for (int i = 0; i < 32; ++i) {
            const float4 kk = *(const float4*)(kr + i * 4);
            const float4 qq = *(const float4*)(qr + i * 4);
            s += kk.x * qq.x + kk.y * qq.y + kk.z * qq.z + kk.w * qq.w;
        }
        s *= SCALE;
        if (j0 + lane > qrow) s = -1e30f;   // causal mask

        // ---- online softmax (per-wave butterflies, width 64) ----
        float mt = s;
        #pragma unroll
        for (int off = 32; off > 0; off >>= 1)
            mt = fmaxf(mt, __shfl_xor(mt, off, 64));
        const float m_new = fmaxf(m_run, mt);
        const float p = __expf(s - m_new);
        float ssum = p;
        #pragma unroll
        for (int off = 32; off > 0; off >>= 1)
            ssum += __shfl_xor(ssum, off, 64);
        const float alpha = __expf(m_run - m_new);
        l_run = l_run * alpha + ssum;
        m_run = m_new;
        acc0 *= alpha;
        acc1 *= alpha;
        ps[w * TS + lane] = p;
        __syncthreads();   // ps write -> cross-lane read ordering

        // ---- PV: lane = d-pair (2*lane, 2*lane+1), loop keys ----
        const float* pw = &ps[w * TS];
        #pragma unroll 8
        for (int j = 0; j < TS; ++j) {
            const float pj = pw[j];
            const float2 vv = *(const float2*)&vs[j * KROWF + 2 * lane];
            acc0 += pj * vv.x;
            acc1 += pj * vv.y;
        }
    }

    const float inv = 1.f / l_run;
    float2 o; o.x = acc0 * inv; o.y = acc1 * inv;
    *(float2*)(out + ((size_t)qrow * NH + h) * HD + 2 * lane) = o;
}

extern "C" void kernel_launch(void* const* d_in, const int* in_sizes, int n_in,
                              void* d_out, int out_size, void* d_ws, size_t ws_size,
                              hipStream_t stream) {
    const float* q = (const float*)d_in[0];
    const float* k = (const float*)d_in[1];
    const float* v = (const float*)d_in[2];
    float* out = (float*)d_out;
    dim3 grid(SEQ / 4, NH);
    attn_fwd<<<grid, dim3(256), 0, stream>>>(q, k, v, out);
}

// Round 3
// 382.258 us; speedup vs baseline: 5.5731x; 5.5731x over previous
//
#include <hip/hip_runtime.h>

// Causal GQA attention prefill, fp32 in/out, MFMA 32x32x16 bf16 compute.
// S=2048, H=32, KVH=8 (rep=4), D=128.
// Round 3: flash attention on the matrix pipe.
//   block = 256 thr = 4 waves, one head, 128 q-rows (32/wave). Key tile 64.
//   K staged [key][d] bf16 stride 136; V staged transposed [d][key] stride 72;
//   both strides = 4 mod 32 dwords -> b128 fragment reads tile all banks.
//   P transposes C-layout -> A-layout through a per-wave LDS buffer (m120).

#define SEQ   2048
#define NH    32
#define NKVH  8
#define HD    128
#define BQ    128
#define BK    64
#define KSS   136   // ks stride (ushort)
#define VTS   72    // vt stride (ushort)
#define PSS   72    // ps stride (ushort)
#define SCALE 0.08838834764831845f

typedef __attribute__((ext_vector_type(8)))  short short8;
typedef __attribute__((ext_vector_type(16))) float float16;

__device__ __forceinline__ unsigned short f2bf(float f) {
    union { float f; unsigned int i; } x; x.f = f;
    unsigned int r = x.i + 0x7fffu + ((x.i >> 16) & 1u);   // RNE
    return (unsigned short)(r >> 16);
}
__device__ __forceinline__ unsigned int f2bf2(float lo, float hi) {
    return (unsigned int)f2bf(lo) | ((unsigned int)f2bf(hi) << 16);
}

__global__ __launch_bounds__(256, 2)
void attn_fwd(const float* __restrict__ q,
              const float* __restrict__ k,
              const float* __restrict__ v,
              float* __restrict__ out)
{
    __shared__ unsigned short ks[BK * KSS];
    __shared__ unsigned short vt[HD * VTS];
    __shared__ unsigned short ps[4][32 * PSS];

    const int t    = threadIdx.x;
    const int w    = t >> 6;
    const int lane = t & 63;
    const int ln   = lane & 31;
    const int half = lane >> 5;
    const int h    = blockIdx.y;
    const int kvh  = h >> 2;          // repeat_interleave rep=4
    const int q0   = blockIdx.x * BQ;
    const int wq0  = q0 + w * 32;     // wave's first q row

    // ---- Q fragments (A-layout: A[m=ln][k=half*8+j]) in regs, once ----
    short8 qf[8];
    {
        const float* qr = q + ((size_t)(wq0 + ln) * NH + h) * HD;
        #pragma unroll
        for (int k0 = 0; k0 < 8; ++k0) {
            const float* p4 = qr + k0 * 16 + half * 8;
            const float4 a = *(const float4*)(p4);
            const float4 b = *(const float4*)(p4 + 4);
            union { short8 v; unsigned int u[4]; } uu;
            uu.u[0] = f2bf2(a.x, a.y);
            uu.u[1] = f2bf2(a.z, a.w);
            uu.u[2] = f2bf2(b.x, b.y);
            uu.u[3] = f2bf2(b.z, b.w);
            qf[k0] = uu.v;
        }
    }

    float16 o0, o1, o2, o3;
    float m_run[16], l_run[16];
    #pragma unroll
    for (int i = 0; i < 16; ++i) {
        o0[i] = 0.f; o1[i] = 0.f; o2[i] = 0.f; o3[i] = 0.f;
        m_run[i] = -1e30f; l_run[i] = 0.f;
    }

    const int ntiles = (q0 + BQ) / BK;
    const int wqmax  = wq0 + 31;

    for (int it = 0; it < ntiles; ++it) {
        const int j0 = it * BK;
        __syncthreads();   // previous tile's fragment reads done

        // ---- stage K: ks[key][d] bf16 ----
        {
            const int key = t >> 2;
            const int db  = (t & 3) * 4;
            const float* kr = k + ((size_t)(j0 + key) * NKVH + kvh) * HD;
            #pragma unroll
            for (int r2 = 0; r2 < 8; ++r2) {
                const int d = db + r2 * 16;
                const float4 a = *(const float4*)(kr + d);
                *(unsigned int*)&ks[key * KSS + d]     = f2bf2(a.x, a.y);
                *(unsigned int*)&ks[key * KSS + d + 2] = f2bf2(a.z, a.w);
            }
        }
        // ---- stage V transposed: vt[d][key] bf16, 2 keys packed/b32 ----
        {
            const int kp = (t & 31) * 2;
            const int db = (t >> 5) * 4;
            const float* vr0 = v + ((size_t)(j0 + kp) * NKVH + kvh) * HD;
            const float* vr1 = vr0 + NKVH * HD;
            #pragma unroll
            for (int r2 = 0; r2 < 4; ++r2) {
                const int d = db + r2 * 32;
                const float4 a = *(const float4*)(vr0 + d);
                const float4 b = *(const float4*)(vr1 + d);
                *(unsigned int*)&vt[(d + 0) * VTS + kp] = f2bf2(a.x, b.x);
                *(unsigned int*)&vt[(d + 1) * VTS + kp] = f2bf2(a.y, b.y);
                *(unsigned int*)&vt[(d + 2) * VTS + kp] = f2bf2(a.z, b.z);
                *(unsigned int*)&vt[(d + 3) * VTS + kp] = f2bf2(a.w, b.w);
            }
        }
        __syncthreads();

        if (j0 > wqmax) continue;   // tile fully masked for this wave

        // ---- S = Q K^T : two 32-key chunks ----
        float16 s0, s1;
        #pragma unroll
        for (int i = 0; i < 16; ++i) { s0[i] = 0.f; s1[i] = 0.f; }
        #pragma unroll
        for (int k0 = 0; k0 < 8; ++k0) {
            const short8 b0 = *(const short8*)&ks[ln * KSS + k0 * 16 + half * 8];
            const short8 b1 = *(const short8*)&ks[(32 + ln) * KSS + k0 * 16 + half * 8];
            s0 = __builtin_amdgcn_mfma_f32_32x32x16_bf16(qf[k0], b0, s0, 0, 0, 0);
            s1 = __builtin_amdgcn_mfma_f32_32x32x16_bf16(qf[k0], b1, s1, 0, 0, 0);
        }

        // ---- online softmax on C-layout; write P to per-wave LDS ----
        const bool need_mask = (j0 + BK - 1) > wq0;
        unsigned short* psw = ps[w];
        #pragma unroll
        for (int r = 0; r < 16; ++r) {
            const int rloc = (r & 3) + 8 * (r >> 2) + 4 * half;
            float a0 = s0[r] * SCALE;
            float a1 = s1[r] * SCALE;
            if (need_mask) {
                const int rowg = wq0 + rloc;
                if (j0 + ln > rowg)      a0 = -1e30f;
                if (j0 + 32 + ln > rowg) a1 = -1e30f;
            }
            float mt = fmaxf(a0, a1);
            #pragma unroll
            for (int off = 1; off < 32; off <<= 1)
                mt = fmaxf(mt, __shfl_xor(mt, off, 64));
            const float mn = fmaxf(m_run[r], mt);
            const float p0 = __expf(a0 - mn);
            const float p1 = __expf(a1 - mn);
            float sm = p0 + p1;
            #pragma unroll
            for (int off = 1; off < 32; off <<= 1)
                sm += __shfl_xor(sm, off, 64);
            const float alpha = __expf(m_run[r] - mn);
            m_run[r] = mn;
            l_run[r] = l_run[r] * alpha + sm;
            o0[r] *= alpha; o1[r] *= alpha; o2[r] *= alpha; o3[r] *= alpha;
            psw[rloc * PSS + ln]      = f2bf(p0);
            psw[rloc * PSS + 32 + ln] = f2bf(p1);
        }

        // ---- PV: A = P (A-layout from LDS), B = V^T ----
        short8 af[4];
        #pragma unroll
        for (int kc = 0; kc < 4; ++kc)
            af[kc] = *(const short8*)&psw[ln * PSS + kc * 16 + half * 8];
        #pragma unroll
        for (int kc = 0; kc < 4; ++kc) {
            const short8 bv0 = *(const short8*)&vt[(ln)      * VTS + kc * 16 + half * 8];
            const short8 bv1 = *(const short8*)&vt[(32 + ln) * VTS + kc * 16 + half * 8];
            const short8 bv2 = *(const short8*)&vt[(64 + ln) * VTS + kc * 16 + half * 8];
            const short8 bv3 = *(const short8*)&vt[(96 + ln) * VTS + kc * 16 + half * 8];
            o0 = __builtin_amdgcn_mfma_f32_32x32x16_bf16(af[kc], bv0, o0, 0, 0, 0);
            o1 = __builtin_amdgcn_mfma_f32_32x32x16_bf16(af[kc], bv1, o1, 0, 0, 0);
            o2 = __builtin_amdgcn_mfma_f32_32x32x16_bf16(af[kc], bv2, o2, 0, 0, 0);
            o3 = __builtin_amdgcn_mfma_f32_32x32x16_bf16(af[kc], bv3, o3, 0, 0, 0);
        }
    }

    // ---- epilogue: normalize + store (fp32, coalesced per 32-lane half) ----
    #pragma unroll
    for (int r = 0; r < 16; ++r) {
        const int rloc = (r & 3) + 8 * (r >> 2) + 4 * half;
        const float inv = 1.f / l_run[r];
        float* orow = out + ((size_t)(wq0 + rloc) * NH + h) * HD;
        orow[ln]      = o0[r] * inv;
        orow[32 + ln] = o1[r] * inv;
        orow[64 + ln] = o2[r] * inv;
        orow[96 + ln] = o3[r] * inv;
    }
}

extern "C" void kernel_launch(void* const* d_in, const int* in_sizes, int n_in,
                              void* d_out, int out_size, void* d_ws, size_t ws_size,
                              hipStream_t stream) {
    const float* q = (const float*)d_in[0];
    const float* k = (const float*)d_in[1];
    const float* v = (const float*)d_in[2];
    float* out = (float*)d_out;
    dim3 grid(SEQ / BQ, NH);
    attn_fwd<<<grid, dim3(256), 0, stream>>>(q, k, v, out);
}

// Round 4
// 216.616 us; speedup vs baseline: 9.8348x; 1.7647x over previous
//
#include <hip/hip_runtime.h>

// Causal GQA attention prefill, fp32 in/out, MFMA 32x32x16 bf16 compute.
// S=2048, H=32, KVH=8 (rep=4), D=128.
// Round 4: S^T formulation. QK^T computed as K*Q^T (operand swap) so the
//   C-layout col (=lane&31) indexes the q-row: softmax over keys reduces
//   over 16 regs (VALU tree) + ONE shfl_xor(32), replacing 160 ds-permutes
//   per tile (round-3 latency killer; MfmaUtil was 4%, VALUBusy 15%).
//   m/l/alpha are per-lane scalars; alpha/l broadcast to the O-accumulator's
//   row indexing through a 32-float per-wave LDS array.

#define SEQ   2048
#define NH    32
#define NKVH  8
#define HD    128
#define BQ    128
#define BK    64
#define KSS   136   // ks stride (ushort)
#define VTS   72    // vt stride (ushort)
#define PSS   72    // ps stride (ushort)
#define SCALE 0.08838834764831845f

typedef __attribute__((ext_vector_type(8)))  short short8;
typedef __attribute__((ext_vector_type(16))) float float16;

__device__ __forceinline__ unsigned short f2bf(float f) {
    union { float f; unsigned int i; } x; x.f = f;
    unsigned int r = x.i + 0x7fffu + ((x.i >> 16) & 1u);   // RNE
    return (unsigned short)(r >> 16);
}
__device__ __forceinline__ unsigned int f2bf2(float lo, float hi) {
    return (unsigned int)f2bf(lo) | ((unsigned int)f2bf(hi) << 16);
}

__global__ __launch_bounds__(256, 2)
void attn_fwd(const float* __restrict__ q,
              const float* __restrict__ k,
              const float* __restrict__ v,
              float* __restrict__ out)
{
    __shared__ unsigned short ks[BK * KSS];
    __shared__ unsigned short vt[HD * VTS];
    __shared__ unsigned short ps[4][32 * PSS];
    __shared__ float          alf[4][32];

    const int t    = threadIdx.x;
    const int w    = t >> 6;
    const int lane = t & 63;
    const int ln   = lane & 31;
    const int half = lane >> 5;
    const int h    = blockIdx.y;
    const int kvh  = h >> 2;          // repeat_interleave rep=4
    const int q0   = blockIdx.x * BQ;
    const int wq0  = q0 + w * 32;     // wave's first q row
    const int qrow = wq0 + ln;        // this lane's q row (dup across halves)

    // ---- Q fragments (lane ln -> Q row wq0+ln, k-range k0*16+half*8) ----
    short8 qf[8];
    {
        const float* qr = q + ((size_t)qrow * NH + h) * HD;
        #pragma unroll
        for (int k0 = 0; k0 < 8; ++k0) {
            const float* p4 = qr + k0 * 16 + half * 8;
            const float4 a = *(const float4*)(p4);
            const float4 b = *(const float4*)(p4 + 4);
            union { short8 v; unsigned int u[4]; } uu;
            uu.u[0] = f2bf2(a.x, a.y);
            uu.u[1] = f2bf2(a.z, a.w);
            uu.u[2] = f2bf2(b.x, b.y);
            uu.u[3] = f2bf2(b.z, b.w);
            qf[k0] = uu.v;
        }
    }

    float16 o0, o1, o2, o3;
    #pragma unroll
    for (int i = 0; i < 16; ++i) { o0[i] = 0.f; o1[i] = 0.f; o2[i] = 0.f; o3[i] = 0.f; }
    float m_run = -1e30f, l_run = 0.f;   // per-lane (per q-row) scalars

    const int ntiles = (q0 + BQ) / BK;
    const int wqmax  = wq0 + 31;

    for (int it = 0; it < ntiles; ++it) {
        const int j0 = it * BK;
        __syncthreads();   // previous tile's fragment reads done

        // ---- stage K: ks[key][d] bf16 ----
        {
            const int key = t >> 2;
            const int db  = (t & 3) * 4;
            const float* kr = k + ((size_t)(j0 + key) * NKVH + kvh) * HD;
            #pragma unroll
            for (int r2 = 0; r2 < 8; ++r2) {
                const int d = db + r2 * 16;
                const float4 a = *(const float4*)(kr + d);
                *(unsigned int*)&ks[key * KSS + d]     = f2bf2(a.x, a.y);
                *(unsigned int*)&ks[key * KSS + d + 2] = f2bf2(a.z, a.w);
            }
        }
        // ---- stage V transposed: vt[d][key] bf16, 2 keys packed/b32 ----
        {
            const int kp = (t & 31) * 2;
            const int db = (t >> 5) * 4;
            const float* vr0 = v + ((size_t)(j0 + kp) * NKVH + kvh) * HD;
            const float* vr1 = vr0 + NKVH * HD;
            #pragma unroll
            for (int r2 = 0; r2 < 4; ++r2) {
                const int d = db + r2 * 32;
                const float4 a = *(const float4*)(vr0 + d);
                const float4 b = *(const float4*)(vr1 + d);
                *(unsigned int*)&vt[(d + 0) * VTS + kp] = f2bf2(a.x, b.x);
                *(unsigned int*)&vt[(d + 1) * VTS + kp] = f2bf2(a.y, b.y);
                *(unsigned int*)&vt[(d + 2) * VTS + kp] = f2bf2(a.z, b.z);
                *(unsigned int*)&vt[(d + 3) * VTS + kp] = f2bf2(a.w, b.w);
            }
        }
        __syncthreads();

        if (j0 > wqmax) continue;   // tile fully masked for this wave

        // ---- S^T = K Q^T : A = K rows, B = Q rows (operand swap) ----
        float16 st0, st1;
        #pragma unroll
        for (int i = 0; i < 16; ++i) { st0[i] = 0.f; st1[i] = 0.f; }
        #pragma unroll
        for (int k0 = 0; k0 < 8; ++k0) {
            const short8 a0 = *(const short8*)&ks[ln * KSS + k0 * 16 + half * 8];
            const short8 a1 = *(const short8*)&ks[(32 + ln) * KSS + k0 * 16 + half * 8];
            st0 = __builtin_amdgcn_mfma_f32_32x32x16_bf16(a0, qf[k0], st0, 0, 0, 0);
            st1 = __builtin_amdgcn_mfma_f32_32x32x16_bf16(a1, qf[k0], st1, 0, 0, 0);
        }

        // ---- scale + causal mask + per-row (=per-lane) online softmax ----
        const bool need_mask = (j0 + BK - 1) > wq0;
        float mt = -1e30f;
        #pragma unroll
        for (int r = 0; r < 16; ++r) {
            const int kl = (r & 3) + 8 * (r >> 2) + 4 * half;   // local key
            float a0 = st0[r] * SCALE;
            float a1 = st1[r] * SCALE;
            if (need_mask) {
                if (j0 + kl > qrow)      a0 = -1e30f;
                if (j0 + 32 + kl > qrow) a1 = -1e30f;
            }
            st0[r] = a0; st1[r] = a1;
            mt = fmaxf(mt, fmaxf(a0, a1));
        }
        mt = fmaxf(mt, __shfl_xor(mt, 32, 64));   // merge halves (disjoint keys)
        const float mn = fmaxf(m_run, mt);
        float sm = 0.f;
        #pragma unroll
        for (int r = 0; r < 16; ++r) {
            const float e0 = __expf(st0[r] - mn);
            const float e1 = __expf(st1[r] - mn);
            st0[r] = e0; st1[r] = e1;
            sm += e0 + e1;
        }
        sm += __shfl_xor(sm, 32, 64);
        const float alpha = __expf(m_run - mn);
        m_run = mn;
        l_run = l_run * alpha + sm;

        // ---- write P (transposed to [qrow][key]) + alpha broadcast ----
        unsigned short* psw = ps[w];
        #pragma unroll
        for (int r = 0; r < 16; r += 2) {
            const int kl = (r & 3) + 8 * (r >> 2) + 4 * half;   // even; r+1 -> kl+1
            *(unsigned int*)&psw[ln * PSS + kl]      = f2bf2(st0[r], st0[r + 1]);
            *(unsigned int*)&psw[ln * PSS + 32 + kl] = f2bf2(st1[r], st1[r + 1]);
        }
        if (half == 0) alf[w][ln] = alpha;
        // same-wave LDS write->read: lockstep + compiler lgkmcnt, no barrier

        // ---- rescale O, then PV: A = P (rows), B = V^T ----
        #pragma unroll
        for (int r = 0; r < 16; ++r) {
            const int rl = (r & 3) + 8 * (r >> 2) + 4 * half;
            const float ar = alf[w][rl];
            o0[r] *= ar; o1[r] *= ar; o2[r] *= ar; o3[r] *= ar;
        }
        short8 af[4];
        #pragma unroll
        for (int kc = 0; kc < 4; ++kc)
            af[kc] = *(const short8*)&psw[ln * PSS + kc * 16 + half * 8];
        #pragma unroll
        for (int kc = 0; kc < 4; ++kc) {
            const short8 bv0 = *(const short8*)&vt[(ln)      * VTS + kc * 16 + half * 8];
            const short8 bv1 = *(const short8*)&vt[(32 + ln) * VTS + kc * 16 + half * 8];
            const short8 bv2 = *(const short8*)&vt[(64 + ln) * VTS + kc * 16 + half * 8];
            const short8 bv3 = *(const short8*)&vt[(96 + ln) * VTS + kc * 16 + half * 8];
            o0 = __builtin_amdgcn_mfma_f32_32x32x16_bf16(af[kc], bv0, o0, 0, 0, 0);
            o1 = __builtin_amdgcn_mfma_f32_32x32x16_bf16(af[kc], bv1, o1, 0, 0, 0);
            o2 = __builtin_amdgcn_mfma_f32_32x32x16_bf16(af[kc], bv2, o2, 0, 0, 0);
            o3 = __builtin_amdgcn_mfma_f32_32x32x16_bf16(af[kc], bv3, o3, 0, 0, 0);
        }
    }

    // ---- epilogue: broadcast l, normalize, store fp32 ----
    if (half == 0) alf[w][ln] = l_run;
    __builtin_amdgcn_s_waitcnt(0);   // wave-local LDS ordering (belt+braces)
    #pragma unroll
    for (int r = 0; r < 16; ++r) {
        const int rl = (r & 3) + 8 * (r >> 2) + 4 * half;
        const float inv = 1.f / alf[w][rl];
        float* orow = out + ((size_t)(wq0 + rl) * NH + h) * HD;
        orow[ln]      = o0[r] * inv;
        orow[32 + ln] = o1[r] * inv;
        orow[64 + ln] = o2[r] * inv;
        orow[96 + ln] = o3[r] * inv;
    }
}

extern "C" void kernel_launch(void* const* d_in, const int* in_sizes, int n_in,
                              void* d_out, int out_size, void* d_ws, size_t ws_size,
                              hipStream_t stream) {
    const float* q = (const float*)d_in[0];
    const float* k = (const float*)d_in[1];
    const float* v = (const float*)d_in[2];
    float* out = (float*)d_out;
    dim3 grid(SEQ / BQ, NH);
    attn_fwd<<<grid, dim3(256), 0, stream>>>(q, k, v, out);
}

// Round 5
// 199.934 us; speedup vs baseline: 10.6554x; 1.0834x over previous
//
#include <hip/hip_runtime.h>

// Causal GQA attention prefill, fp32 in/out, MFMA 32x32x16 bf16 compute.
// S=2048, H=32, KVH=8 (rep=4), D=128.
// Round 5 on top of round 4's S^T formulation:
//   1) K/V pre-converted to bf16 ONCE into d_ws (K natural; V transposed
//      into LDS-shaped [kvh][jt][d][key] tiles) -> hot-loop staging is a
//      pure copy, no f2bf VALU (round-4's VALUBusy was staging-conversion).
//   2) Work-complementary pairing: grid=512; blocks i and i+256 (same CU
//      under round-robin dispatch) take q-tiles px and 15-px -> 34 key-tile
//      units per CU uniformly (round-4 Occupancy=11% was tail imbalance).
//   3) Register prefetch of tile it+1 issued before compute of tile it.

#define SEQ   2048
#define NH    32
#define NKVH  8
#define HD    128
#define BQ    128
#define BK    64
#define KSS   136   // ks stride (ushort)
#define VTS   72    // vt stride (ushort)
#define PSS   72    // ps stride (ushort)
#define SCALE 0.08838834764831845f

#define KB_ELEMS (SEQ * NKVH * HD)          // 2,097,152 ushorts
#define WS_NEED  (2u * KB_ELEMS * 2u)       // kb + vtw, bytes

typedef __attribute__((ext_vector_type(8)))  short short8;
typedef __attribute__((ext_vector_type(16))) float float16;

__device__ __forceinline__ unsigned short f2bf(float f) {
    union { float f; unsigned int i; } x; x.f = f;
    unsigned int r = x.i + 0x7fffu + ((x.i >> 16) & 1u);   // RNE
    return (unsigned short)(r >> 16);
}
__device__ __forceinline__ unsigned int f2bf2(float lo, float hi) {
    return (unsigned int)f2bf(lo) | ((unsigned int)f2bf(hi) << 16);
}

// ---- prep: K fp32 -> bf16, natural [s][kvh][d] ----
__global__ __launch_bounds__(256)
void cvt_k(const float* __restrict__ k, unsigned short* __restrict__ kb)
{
    const int i = (blockIdx.x * 256 + threadIdx.x) * 4;
    const float4 a = *(const float4*)(k + i);
    uint2 o; o.x = f2bf2(a.x, a.y); o.y = f2bf2(a.z, a.w);
    *(uint2*)(kb + i) = o;
}

// ---- prep: V fp32 -> bf16 transposed tiles vtw[kvh][jt][d][key64] ----
__global__ __launch_bounds__(256)
void cvt_v(const float* __restrict__ v, unsigned short* __restrict__ vtw)
{
    __shared__ unsigned short tl[HD * VTS];
    const int t   = threadIdx.x;
    const int jt  = blockIdx.x & 31;
    const int kvh = blockIdx.x >> 5;
    const int dp  = (t & 63) * 2;
    const int k0  = t >> 6;
    #pragma unroll
    for (int r = 0; r < 16; ++r) {
        const int key = k0 + r * 4;
        const float2 a =
            *(const float2*)(v + ((size_t)(jt * 64 + key) * NKVH + kvh) * HD + dp);
        tl[dp * VTS + key]       = f2bf(a.x);
        tl[(dp + 1) * VTS + key] = f2bf(a.y);
    }
    __syncthreads();
    unsigned short* dst = vtw + (size_t)(kvh * 32 + jt) * HD * 64;
    const int c  = t & 7;
    const int d0 = t >> 3;
    #pragma unroll
    for (int r = 0; r < 4; ++r) {
        const int d = d0 + r * 32;
        *(uint4*)(dst + d * 64 + c * 8) = *(const uint4*)&tl[d * VTS + c * 8];
    }
}

// ---- main ----
__global__ __launch_bounds__(256, 2)
void attn_fwd2(const float* __restrict__ q,
               const unsigned short* __restrict__ kb,
               const unsigned short* __restrict__ vtw,
               float* __restrict__ out)
{
    __shared__ unsigned short ks[BK * KSS];
    __shared__ unsigned short vt[HD * VTS];
    __shared__ unsigned short ps[4][32 * PSS];
    __shared__ float          alf[4][32];

    const int t    = threadIdx.x;
    const int w    = t >> 6;
    const int lane = t & 63;
    const int ln   = lane & 31;
    const int half = lane >> 5;

    // work-complementary pairing: blocks i and i+256 -> q-tiles px, 15-px
    const int pair = blockIdx.x & 255;
    const int late = blockIdx.x >> 8;
    const int h    = pair & 31;
    const int px   = pair >> 5;                 // 0..7
    const int bx   = late ? (15 - px) : px;
    const int kvh  = h >> 2;                    // repeat_interleave rep=4
    const int q0   = bx * BQ;
    const int wq0  = q0 + w * 32;
    const int qrow = wq0 + ln;
    const int ntiles = q0 / BK + 2;
    const int wqmax  = wq0 + 31;

    // staging decompositions
    const int skey = t >> 2, sc = t & 3;        // K: 4 thr/key, 16B chunks
    const int vc = t & 7, vd0 = t >> 3;         // V: linear copy rows
    const unsigned short* vtile0 = vtw + (size_t)(kvh * 32) * HD * 64;

    // ---- Q fragments (lane ln -> Q row wq0+ln) ----
    short8 qf[8];
    {
        const float* qr = q + ((size_t)qrow * NH + h) * HD;
        #pragma unroll
        for (int k0 = 0; k0 < 8; ++k0) {
            const float* p4 = qr + k0 * 16 + half * 8;
            const float4 a = *(const float4*)(p4);
            const float4 b = *(const float4*)(p4 + 4);
            union { short8 v; unsigned int u[4]; } uu;
            uu.u[0] = f2bf2(a.x, a.y);
            uu.u[1] = f2bf2(a.z, a.w);
            uu.u[2] = f2bf2(b.x, b.y);
            uu.u[3] = f2bf2(b.z, b.w);
            qf[k0] = uu.v;
        }
    }

    float16 o0, o1, o2, o3;
    #pragma unroll
    for (int i = 0; i < 16; ++i) { o0[i] = 0.f; o1[i] = 0.f; o2[i] = 0.f; o3[i] = 0.f; }
    float m_run = -1e30f, l_run = 0.f;

    // ---- prefetch tile 0 into registers ----
    uint4 kpre[4], vpre[4];
    {
        const unsigned short* krow = kb + ((size_t)skey * NKVH + kvh) * HD + sc * 8;
        #pragma unroll
        for (int r = 0; r < 4; ++r) kpre[r] = *(const uint4*)(krow + r * 32);
        #pragma unroll
        for (int r = 0; r < 4; ++r)
            vpre[r] = *(const uint4*)(vtile0 + (size_t)t * 8 + r * 2048);
    }

    for (int it = 0; it < ntiles; ++it) {
        const int j0 = it * BK;
        __syncthreads();   // previous tile's fragment reads done

        // ---- write prefetched tile to LDS (pure copy) ----
        #pragma unroll
        for (int r = 0; r < 4; ++r)
            *(uint4*)&ks[skey * KSS + sc * 8 + r * 32] = kpre[r];
        #pragma unroll
        for (int r = 0; r < 4; ++r)
            *(uint4*)&vt[(vd0 + r * 32) * VTS + vc * 8] = vpre[r];

        // ---- prefetch next tile (overlaps with compute below) ----
        if (it + 1 < ntiles) {
            const int j1 = j0 + BK;
            const unsigned short* krow =
                kb + ((size_t)(j1 + skey) * NKVH + kvh) * HD + sc * 8;
            #pragma unroll
            for (int r = 0; r < 4; ++r) kpre[r] = *(const uint4*)(krow + r * 32);
            const unsigned short* vtile = vtile0 + (size_t)(it + 1) * HD * 64;
            #pragma unroll
            for (int r = 0; r < 4; ++r)
                vpre[r] = *(const uint4*)(vtile + (size_t)t * 8 + r * 2048);
        }
        __syncthreads();

        if (j0 > wqmax) continue;   // tile fully masked for this wave

        // ---- S^T = K Q^T ----
        float16 st0, st1;
        #pragma unroll
        for (int i = 0; i < 16; ++i) { st0[i] = 0.f; st1[i] = 0.f; }
        #pragma unroll
        for (int k0 = 0; k0 < 8; ++k0) {
            const short8 a0 = *(const short8*)&ks[ln * KSS + k0 * 16 + half * 8];
            const short8 a1 = *(const short8*)&ks[(32 + ln) * KSS + k0 * 16 + half * 8];
            st0 = __builtin_amdgcn_mfma_f32_32x32x16_bf16(a0, qf[k0], st0, 0, 0, 0);
            st1 = __builtin_amdgcn_mfma_f32_32x32x16_bf16(a1, qf[k0], st1, 0, 0, 0);
        }

        // ---- scale + mask + per-lane online softmax ----
        const bool need_mask = (j0 + BK - 1) > wq0;
        float mt = -1e30f;
        #pragma unroll
        for (int r = 0; r < 16; ++r) {
            const int kl = (r & 3) + 8 * (r >> 2) + 4 * half;
            float a0 = st0[r] * SCALE;
            float a1 = st1[r] * SCALE;
            if (need_mask) {
                if (j0 + kl > qrow)      a0 = -1e30f;
                if (j0 + 32 + kl > qrow) a1 = -1e30f;
            }
            st0[r] = a0; st1[r] = a1;
            mt = fmaxf(mt, fmaxf(a0, a1));
        }
        mt = fmaxf(mt, __shfl_xor(mt, 32, 64));
        const float mn = fmaxf(m_run, mt);
        float sm = 0.f;
        #pragma unroll
        for (int r = 0; r < 16; ++r) {
            const float e0 = __expf(st0[r] - mn);
            const float e1 = __expf(st1[r] - mn);
            st0[r] = e0; st1[r] = e1;
            sm += e0 + e1;
        }
        sm += __shfl_xor(sm, 32, 64);
        const float alpha = __expf(m_run - mn);
        m_run = mn;
        l_run = l_run * alpha + sm;

        // ---- write P^T->[qrow][key] + alpha broadcast ----
        unsigned short* psw = ps[w];
        #pragma unroll
        for (int r = 0; r < 16; r += 2) {
            const int kl = (r & 3) + 8 * (r >> 2) + 4 * half;
            *(unsigned int*)&psw[ln * PSS + kl]      = f2bf2(st0[r], st0[r + 1]);
            *(unsigned int*)&psw[ln * PSS + 32 + kl] = f2bf2(st1[r], st1[r + 1]);
        }
        if (half == 0) alf[w][ln] = alpha;

        // ---- rescale O, PV ----
        #pragma unroll
        for (int r = 0; r < 16; ++r) {
            const int rl = (r & 3) + 8 * (r >> 2) + 4 * half;
            const float ar = alf[w][rl];
            o0[r] *= ar; o1[r] *= ar; o2[r] *= ar; o3[r] *= ar;
        }
        short8 af[4];
        #pragma unroll
        for (int kc = 0; kc < 4; ++kc)
            af[kc] = *(const short8*)&psw[ln * PSS + kc * 16 + half * 8];
        #pragma unroll
        for (int kc = 0; kc < 4; ++kc) {
            const short8 bv0 = *(const short8*)&vt[(ln)      * VTS + kc * 16 + half * 8];
            const short8 bv1 = *(const short8*)&vt[(32 + ln) * VTS + kc * 16 + half * 8];
            const short8 bv2 = *(const short8*)&vt[(64 + ln) * VTS + kc * 16 + half * 8];
            const short8 bv3 = *(const short8*)&vt[(96 + ln) * VTS + kc * 16 + half * 8];
            o0 = __builtin_amdgcn_mfma_f32_32x32x16_bf16(af[kc], bv0, o0, 0, 0, 0);
            o1 = __builtin_amdgcn_mfma_f32_32x32x16_bf16(af[kc], bv1, o1, 0, 0, 0);
            o2 = __builtin_amdgcn_mfma_f32_32x32x16_bf16(af[kc], bv2, o2, 0, 0, 0);
            o3 = __builtin_amdgcn_mfma_f32_32x32x16_bf16(af[kc], bv3, o3, 0, 0, 0);
        }
    }

    // ---- epilogue ----
    if (half == 0) alf[w][ln] = l_run;
    __builtin_amdgcn_s_waitcnt(0);
    #pragma unroll
    for (int r = 0; r < 16; ++r) {
        const int rl = (r & 3) + 8 * (r >> 2) + 4 * half;
        const float inv = 1.f / alf[w][rl];
        float* orow = out + ((size_t)(wq0 + rl) * NH + h) * HD;
        orow[ln]      = o0[r] * inv;
        orow[32 + ln] = o1[r] * inv;
        orow[64 + ln] = o2[r] * inv;
        orow[96 + ln] = o3[r] * inv;
    }
}

// ---- fallback (round-4 kernel, no workspace needed) ----
__global__ __launch_bounds__(256, 2)
void attn_fwd_fb(const float* __restrict__ q,
                 const float* __restrict__ k,
                 const float* __restrict__ v,
                 float* __restrict__ out)
{
    __shared__ unsigned short ks[BK * KSS];
    __shared__ unsigned short vt[HD * VTS];
    __shared__ unsigned short ps[4][32 * PSS];
    __shared__ float          alf[4][32];

    const int t    = threadIdx.x;
    const int w    = t >> 6;
    const int lane = t & 63;
    const int ln   = lane & 31;
    const int half = lane >> 5;
    const int h    = blockIdx.y;
    const int kvh  = h >> 2;
    const int q0   = blockIdx.x * BQ;
    const int wq0  = q0 + w * 32;
    const int qrow = wq0 + ln;

    short8 qf[8];
    {
        const float* qr = q + ((size_t)qrow * NH + h) * HD;
        #pragma unroll
        for (int k0 = 0; k0 < 8; ++k0) {
            const float* p4 = qr + k0 * 16 + half * 8;
            const float4 a = *(const float4*)(p4);
            const float4 b = *(const float4*)(p4 + 4);
            union { short8 v; unsigned int u[4]; } uu;
            uu.u[0] = f2bf2(a.x, a.y);
            uu.u[1] = f2bf2(a.z, a.w);
            uu.u[2] = f2bf2(b.x, b.y);
            uu.u[3] = f2bf2(b.z, b.w);
            qf[k0] = uu.v;
        }
    }

    float16 o0, o1, o2, o3;
    #pragma unroll
    for (int i = 0; i < 16; ++i) { o0[i] = 0.f; o1[i] = 0.f; o2[i] = 0.f; o3[i] = 0.f; }
    float m_run = -1e30f, l_run = 0.f;
    const int ntiles = (q0 + BQ) / BK;
    const int wqmax  = wq0 + 31;

    for (int it = 0; it < ntiles; ++it) {
        const int j0 = it * BK;
        __syncthreads();
        {
            const int key = t >> 2;
            const int db  = (t & 3) * 4;
            const float* kr = k + ((size_t)(j0 + key) * NKVH + kvh) * HD;
            #pragma unroll
            for (int r2 = 0; r2 < 8; ++r2) {
                const int d = db + r2 * 16;
                const float4 a = *(const float4*)(kr + d);
                *(unsigned int*)&ks[key * KSS + d]     = f2bf2(a.x, a.y);
                *(unsigned int*)&ks[key * KSS + d + 2] = f2bf2(a.z, a.w);
            }
        }
        {
            const int kp = (t & 31) * 2;
            const int db = (t >> 5) * 4;
            const float* vr0 = v + ((size_t)(j0 + kp) * NKVH + kvh) * HD;
            const float* vr1 = vr0 + NKVH * HD;
            #pragma unroll
            for (int r2 = 0; r2 < 4; ++r2) {
                const int d = db + r2 * 32;
                const float4 a = *(const float4*)(vr0 + d);
                const float4 b = *(const float4*)(vr1 + d);
                *(unsigned int*)&vt[(d + 0) * VTS + kp] = f2bf2(a.x, b.x);
                *(unsigned int*)&vt[(d + 1) * VTS + kp] = f2bf2(a.y, b.y);
                *(unsigned int*)&vt[(d + 2) * VTS + kp] = f2bf2(a.z, b.z);
                *(unsigned int*)&vt[(d + 3) * VTS + kp] = f2bf2(a.w, b.w);
            }
        }
        __syncthreads();
        if (j0 > wqmax) continue;

        float16 st0, st1;
        #pragma unroll
        for (int i = 0; i < 16; ++i) { st0[i] = 0.f; st1[i] = 0.f; }
        #pragma unroll
        for (int k0 = 0; k0 < 8; ++k0) {
            const short8 a0 = *(const short8*)&ks[ln * KSS + k0 * 16 + half * 8];
            const short8 a1 = *(const short8*)&ks[(32 + ln) * KSS + k0 * 16 + half * 8];
            st0 = __builtin_amdgcn_mfma_f32_32x32x16_bf16(a0, qf[k0], st0, 0, 0, 0);
            st1 = __builtin_amdgcn_mfma_f32_32x32x16_bf16(a1, qf[k0], st1, 0, 0, 0);
        }
        const bool need_mask = (j0 + BK - 1) > wq0;
        float mt = -1e30f;
        #pragma unroll
        for (int r = 0; r < 16; ++r) {
            const int kl = (r & 3) + 8 * (r >> 2) + 4 * half;
            float a0 = st0[r] * SCALE;
            float a1 = st1[r] * SCALE;
            if (need_mask) {
                if (j0 + kl > qrow)      a0 = -1e30f;
                if (j0 + 32 + kl > qrow) a1 = -1e30f;
            }
            st0[r] = a0; st1[r] = a1;
            mt = fmaxf(mt, fmaxf(a0, a1));
        }
        mt = fmaxf(mt, __shfl_xor(mt, 32, 64));
        const float mn = fmaxf(m_run, mt);
        float sm = 0.f;
        #pragma unroll
        for (int r = 0; r < 16; ++r) {
            const float e0 = __expf(st0[r] - mn);
            const float e1 = __expf(st1[r] - mn);
            st0[r] = e0; st1[r] = e1;
            sm += e0 + e1;
        }
        sm += __shfl_xor(sm, 32, 64);
        const float alpha = __expf(m_run - mn);
        m_run = mn;
        l_run = l_run * alpha + sm;

        unsigned short* psw = ps[w];
        #pragma unroll
        for (int r = 0; r < 16; r += 2) {
            const int kl = (r & 3) + 8 * (r >> 2) + 4 * half;
            *(unsigned int*)&psw[ln * PSS + kl]      = f2bf2(st0[r], st0[r + 1]);
            *(unsigned int*)&psw[ln * PSS + 32 + kl] = f2bf2(st1[r], st1[r + 1]);
        }
        if (half == 0) alf[w][ln] = alpha;
        #pragma unroll
        for (int r = 0; r < 16; ++r) {
            const int rl = (r & 3) + 8 * (r >> 2) + 4 * half;
            const float ar = alf[w][rl];
            o0[r] *= ar; o1[r] *= ar; o2[r] *= ar; o3[r] *= ar;
        }
        short8 af[4];
        #pragma unroll
        for (int kc = 0; kc < 4; ++kc)
            af[kc] = *(const short8*)&psw[ln * PSS + kc * 16 + half * 8];
        #pragma unroll
        for (int kc = 0; kc < 4; ++kc) {
            const short8 bv0 = *(const short8*)&vt[(ln)      * VTS + kc * 16 + half * 8];
            const short8 bv1 = *(const short8*)&vt[(32 + ln) * VTS + kc * 16 + half * 8];
            const short8 bv2 = *(const short8*)&vt[(64 + ln) * VTS + kc * 16 + half * 8];
            const short8 bv3 = *(const short8*)&vt[(96 + ln) * VTS + kc * 16 + half * 8];
            o0 = __builtin_amdgcn_mfma_f32_32x32x16_bf16(af[kc], bv0, o0, 0, 0, 0);
            o1 = __builtin_amdgcn_mfma_f32_32x32x16_bf16(af[kc], bv1, o1, 0, 0, 0);
            o2 = __builtin_amdgcn_mfma_f32_32x32x16_bf16(af[kc], bv2, o2, 0, 0, 0);
            o3 = __builtin_amdgcn_mfma_f32_32x32x16_bf16(af[kc], bv3, o3, 0, 0, 0);
        }
    }

    if (half == 0) alf[w][ln] = l_run;
    __builtin_amdgcn_s_waitcnt(0);
    #pragma unroll
    for (int r = 0; r < 16; ++r) {
        const int rl = (r & 3) + 8 * (r >> 2) + 4 * half;
        const float inv = 1.f / alf[w][rl];
        float* orow = out + ((size_t)(wq0 + rl) * NH + h) * HD;
        orow[ln]      = o0[r] * inv;
        orow[32 + ln] = o1[r] * inv;
        orow[64 + ln] = o2[r] * inv;
        orow[96 + ln] = o3[r] * inv;
    }
}

extern "C" void kernel_launch(void* const* d_in, const int* in_sizes, int n_in,
                              void* d_out, int out_size, void* d_ws, size_t ws_size,
                              hipStream_t stream) {
    const float* q = (const float*)d_in[0];
    const float* k = (const float*)d_in[1];
    const float* v = (const float*)d_in[2];
    float* out = (float*)d_out;
    if (ws_size >= (size_t)WS_NEED) {
        unsigned short* kb  = (unsigned short*)d_ws;
        unsigned short* vtw = kb + KB_ELEMS;
        cvt_k<<<KB_ELEMS / (256 * 4), 256, 0, stream>>>(k, kb);
        cvt_v<<<NKVH * 32, 256, 0, stream>>>(v, vtw);
        attn_fwd2<<<512, 256, 0, stream>>>(q, kb, vtw, out);
    } else {
        attn_fwd_fb<<<dim3(SEQ / BQ, NH), 256, 0, stream>>>(q, k, v, out);
    }
}